// Round 2
// baseline (5523.662 us; speedup 1.0000x reference)
//
#include <hip/hip_runtime.h>
#include <stdint.h>

#define NN 100000
#define NE 3200000
#define KF 256   // in features
#define MF 128   // out features

typedef __attribute__((ext_vector_type(8))) short bf16x8;
typedef __attribute__((ext_vector_type(4))) float floatx4;

__device__ __forceinline__ float bf2f(unsigned short u) {
  union { unsigned int i; float f; } w; w.i = ((unsigned int)u) << 16; return w.f;
}
__device__ __forceinline__ unsigned short f2bf(float f) {
  union { float f; unsigned int i; } w; w.f = f;
  unsigned int u = w.i;
  u += 0x7FFFu + ((u >> 16) & 1u);   // round-to-nearest-even
  return (unsigned short)(u >> 16);
}

// ---- Kernel 0: W [K=256][M=128] fp32 -> Wt [M=128][K=256] bf16 ----
__global__ __launch_bounds__(256) void wt_kernel(const float* __restrict__ W,
                                                 unsigned short* __restrict__ Wt) {
  int idx = blockIdx.x * 256 + threadIdx.x;   // 32768 total
  int k = idx >> 7;
  int c = idx & 127;
  Wt[(size_t)c * KF + k] = f2bf(W[(size_t)k * MF + c]);
}

// ---- Kernel 1: support = x @ W + b (fp32 in -> bf16 staging -> MFMA fp32 acc -> bf16 out)
// block: 256 threads = 4 waves; 64 rows x 128 cols per block; K in 2 chunks of 128
__global__ __launch_bounds__(256) void gemm_kernel(const float* __restrict__ x,
                                                   const unsigned short* __restrict__ Wt,
                                                   const float* __restrict__ bias,
                                                   unsigned short* __restrict__ support) {
  __shared__ unsigned short Ax[64][136];    // 64 rows x 128 k (bf16), pad->136
  __shared__ unsigned short Wl[128][136];   // 128 cols x 128 k (bf16)
  const int tid = threadIdx.x;
  const int row0 = blockIdx.x * 64;
  const int lane = tid & 63;
  const int wv = tid >> 6;        // wave 0..3
  const int m = lane & 15;
  const int quad = lane >> 4;     // 0..3

  floatx4 acc[8];
#pragma unroll
  for (int t = 0; t < 8; ++t) acc[t] = (floatx4){0.f, 0.f, 0.f, 0.f};

  for (int kb = 0; kb < 2; ++kb) {
    if (kb) __syncthreads();
    // stage A chunk: 64 rows x 128 k fp32 -> bf16. 2048 float4 units, 8/thread
#pragma unroll
    for (int i = 0; i < 8; ++i) {
      int u = tid + i * 256;
      int r = u >> 5;             // 0..63
      int q = u & 31;             // float4 unit within 128-float chunk
      float4 v = make_float4(0.f, 0.f, 0.f, 0.f);
      if (row0 + r < NN)
        v = *(const float4*)(x + (size_t)(row0 + r) * KF + kb * 128 + q * 4);
      ushort4 p;
      p.x = f2bf(v.x); p.y = f2bf(v.y); p.z = f2bf(v.z); p.w = f2bf(v.w);
      *(ushort4*)(&Ax[r][q * 4]) = p;
    }
    // stage Wt chunk (already bf16): 128 cols x 128 k = 2048 x 16B units, 8/thread
#pragma unroll
    for (int i = 0; i < 8; ++i) {
      int u = tid + i * 256;
      int c = u >> 4, kq = u & 15;
      *(uint4*)(&Wl[c][kq * 8]) = *(const uint4*)(Wt + (size_t)c * KF + kb * 128 + kq * 8);
    }
    __syncthreads();
#pragma unroll
    for (int kc = 0; kc < 4; ++kc) {
      int k0 = kc * 32 + quad * 8;
      bf16x8 af = *(const bf16x8*)(&Ax[wv * 16 + m][k0]);
#pragma unroll
      for (int ct = 0; ct < 8; ++ct) {
        bf16x8 bfv = *(const bf16x8*)(&Wl[ct * 16 + m][k0]);
        acc[ct] = __builtin_amdgcn_mfma_f32_16x16x32_bf16(af, bfv, acc[ct], 0, 0, 0);
      }
    }
  }
  // epilogue: D mapping col=lane&15, row=quad*4+reg (verified m89/m91)
#pragma unroll
  for (int ct = 0; ct < 8; ++ct) {
    int col = ct * 16 + m;
    float bv = bias[col];
#pragma unroll
    for (int rg = 0; rg < 4; ++rg) {
      int grow = row0 + wv * 16 + quad * 4 + rg;
      if (grow < NN)
        support[(size_t)grow * MF + col] = f2bf(acc[ct][rg] + bv);
    }
  }
}

// ---- Kernel 2: edge-parallel scatter-add, fp32 atomics directly into d_out ----
// 32 lanes per edge, each lane covers 4 output columns
__global__ __launch_bounds__(256) void spmm_kernel(const int* __restrict__ rows,
                                                   const int* __restrict__ cols,
                                                   const float* __restrict__ vals,
                                                   const unsigned short* __restrict__ support,
                                                   float* __restrict__ out) {
  unsigned long long gid = (unsigned long long)blockIdx.x * 256ull + threadIdx.x;
  unsigned int e = (unsigned int)(gid >> 5);
  if (e >= NE) return;
  int l = (int)(gid & 31);
  int r = rows[e];
  int c = cols[e];
  float v = vals[e];
  ushort4 s = *(const ushort4*)(support + (size_t)c * MF + l * 4);
  float* op = out + (size_t)r * MF + l * 4;
  unsafeAtomicAdd(op + 0, v * bf2f(s.x));
  unsafeAtomicAdd(op + 1, v * bf2f(s.y));
  unsafeAtomicAdd(op + 2, v * bf2f(s.z));
  unsafeAtomicAdd(op + 3, v * bf2f(s.w));
}

extern "C" void kernel_launch(void* const* d_in, const int* in_sizes, int n_in,
                              void* d_out, int out_size, void* d_ws, size_t ws_size,
                              hipStream_t stream) {
  const float* x    = (const float*)d_in[0];
  const int*   rows = (const int*)d_in[1];
  const int*   cols = (const int*)d_in[2];
  const float* vals = (const float*)d_in[3];
  const float* W    = (const float*)d_in[4];
  const float* bias = (const float*)d_in[5];

  char* ws = (char*)d_ws;
  unsigned short* Wt      = (unsigned short*)ws;             // 65,536 B
  unsigned short* support = (unsigned short*)(ws + 65536);   // 25,600,000 B

  // output accumulates in-place in d_out (fp32); harness poisons it, so zero it
  hipMemsetAsync(d_out, 0, (size_t)out_size * sizeof(float), stream);

  wt_kernel<<<128, 256, 0, stream>>>(W, Wt);
  gemm_kernel<<<(NN + 63) / 64, 256, 0, stream>>>(x, Wt, bias, support);
  spmm_kernel<<<(NE * 32) / 256, 256, 0, stream>>>(rows, cols, vals, support, (float*)d_out);
}

// Round 3
// 695.626 us; speedup vs baseline: 7.9406x; 7.9406x over previous
//
#include <hip/hip_runtime.h>
#include <stdint.h>

#define NN 100000
#define NE 3200000
#define KF 256   // in features
#define MF 128   // out features

typedef __attribute__((ext_vector_type(8))) short bf16x8;
typedef __attribute__((ext_vector_type(4))) float floatx4;

__device__ __forceinline__ float bf2f(unsigned short u) {
  union { unsigned int i; float f; } w; w.i = ((unsigned int)u) << 16; return w.f;
}
__device__ __forceinline__ unsigned short f2bf(float f) {
  union { float f; unsigned int i; } w; w.f = f;
  unsigned int u = w.i;
  u += 0x7FFFu + ((u >> 16) & 1u);   // round-to-nearest-even
  return (unsigned short)(u >> 16);
}

// ---- Kernel 0: W [K=256][M=128] fp32 -> Wt [M=128][K=256] bf16 ----
__global__ __launch_bounds__(256) void wt_kernel(const float* __restrict__ W,
                                                 unsigned short* __restrict__ Wt) {
  int idx = blockIdx.x * 256 + threadIdx.x;   // 32768 total
  int k = idx >> 7;
  int c = idx & 127;
  Wt[(size_t)c * KF + k] = f2bf(W[(size_t)k * MF + c]);
}

// ---- Kernel 1: support = x @ W + b (fp32 -> bf16 staging -> MFMA -> bf16) ----
__global__ __launch_bounds__(256) void gemm_kernel(const float* __restrict__ x,
                                                   const unsigned short* __restrict__ Wt,
                                                   const float* __restrict__ bias,
                                                   unsigned short* __restrict__ support) {
  __shared__ unsigned short Ax[64][136];
  __shared__ unsigned short Wl[128][136];
  const int tid = threadIdx.x;
  const int row0 = blockIdx.x * 64;
  const int lane = tid & 63;
  const int wv = tid >> 6;
  const int m = lane & 15;
  const int quad = lane >> 4;

  floatx4 acc[8];
#pragma unroll
  for (int t = 0; t < 8; ++t) acc[t] = (floatx4){0.f, 0.f, 0.f, 0.f};

  for (int kb = 0; kb < 2; ++kb) {
    if (kb) __syncthreads();
#pragma unroll
    for (int i = 0; i < 8; ++i) {
      int u = tid + i * 256;
      int r = u >> 5;
      int q = u & 31;
      float4 v = make_float4(0.f, 0.f, 0.f, 0.f);
      if (row0 + r < NN)
        v = *(const float4*)(x + (size_t)(row0 + r) * KF + kb * 128 + q * 4);
      ushort4 p;
      p.x = f2bf(v.x); p.y = f2bf(v.y); p.z = f2bf(v.z); p.w = f2bf(v.w);
      *(ushort4*)(&Ax[r][q * 4]) = p;
    }
#pragma unroll
    for (int i = 0; i < 8; ++i) {
      int u = tid + i * 256;
      int c = u >> 4, kq = u & 15;
      *(uint4*)(&Wl[c][kq * 8]) = *(const uint4*)(Wt + (size_t)c * KF + kb * 128 + kq * 8);
    }
    __syncthreads();
#pragma unroll
    for (int kc = 0; kc < 4; ++kc) {
      int k0 = kc * 32 + quad * 8;
      bf16x8 af = *(const bf16x8*)(&Ax[wv * 16 + m][k0]);
#pragma unroll
      for (int ct = 0; ct < 8; ++ct) {
        bf16x8 bfv = *(const bf16x8*)(&Wl[ct * 16 + m][k0]);
        acc[ct] = __builtin_amdgcn_mfma_f32_16x16x32_bf16(af, bfv, acc[ct], 0, 0, 0);
      }
    }
  }
#pragma unroll
  for (int ct = 0; ct < 8; ++ct) {
    int col = ct * 16 + m;
    float bv = bias[col];
#pragma unroll
    for (int rg = 0; rg < 4; ++rg) {
      int grow = row0 + wv * 16 + quad * 4 + rg;
      if (grow < NN)
        support[(size_t)grow * MF + col] = f2bf(acc[ct][rg] + bv);
    }
  }
}

// ---- Kernel 2: histogram of destination rows ----
__global__ __launch_bounds__(256) void hist_kernel(const int* __restrict__ rows,
                                                   unsigned int* __restrict__ cnt) {
  unsigned int e = blockIdx.x * 256 + threadIdx.x;
  if (e < NE) atomicAdd(&cnt[rows[e]], 1u);
}

// ---- Kernel 3: single-block exclusive scan of cnt[0..NN) -> row_start ----
// 1024 threads, 4 elems/thread, 25 chunk iterations with running carry
__global__ __launch_bounds__(1024) void scan_kernel(const unsigned int* __restrict__ cnt,
                                                    unsigned int* __restrict__ row_start) {
  __shared__ unsigned int wsum[16];
  __shared__ unsigned int carry_s;
  const int tid = threadIdx.x;
  const int lane = tid & 63;
  const int wv = tid >> 6;
  if (tid == 0) carry_s = 0;
  __syncthreads();
  for (int base = 0; base < NN; base += 4096) {
    int gi = base + tid * 4;
    uint4 v = make_uint4(0u, 0u, 0u, 0u);
    if (gi + 3 < NN) {
      v = *(const uint4*)(cnt + gi);
    } else {
      if (gi + 0 < NN) v.x = cnt[gi + 0];
      if (gi + 1 < NN) v.y = cnt[gi + 1];
      if (gi + 2 < NN) v.z = cnt[gi + 2];
      if (gi + 3 < NN) v.w = cnt[gi + 3];
    }
    unsigned int s0 = v.x;
    unsigned int s1 = s0 + v.y;
    unsigned int s2 = s1 + v.z;
    unsigned int t  = s2 + v.w;          // thread total
    unsigned int inc = t;                 // wave inclusive scan of totals
#pragma unroll
    for (int d = 1; d < 64; d <<= 1) {
      unsigned int n = __shfl_up(inc, d, 64);
      if (lane >= d) inc += n;
    }
    if (lane == 63) wsum[wv] = inc;
    __syncthreads();
    if (wv == 0 && lane < 16) {
      unsigned int w = wsum[lane];
      unsigned int winc = w;
#pragma unroll
      for (int d = 1; d < 16; d <<= 1) {
        unsigned int n = __shfl_up(winc, d, 64);
        if (lane >= d) winc += n;
      }
      wsum[lane] = winc - w;             // exclusive wave prefix
    }
    __syncthreads();
    unsigned int base_off = carry_s + wsum[wv] + (inc - t);
    if (gi + 0 < NN) row_start[gi + 0] = base_off;
    if (gi + 1 < NN) row_start[gi + 1] = base_off + s0;
    if (gi + 2 < NN) row_start[gi + 2] = base_off + s1;
    if (gi + 3 < NN) row_start[gi + 3] = base_off + s2;
    __syncthreads();
    if (tid == 1023) carry_s += wsum[15] + inc;   // inc == wave-15 total here
    __syncthreads();
  }
  if (tid == 0) row_start[NN] = NE;
}

// ---- Kernel 4: scatter edges into row-binned array (packed col+val, 8 B) ----
__global__ __launch_bounds__(256) void scatter_kernel(const int* __restrict__ rows,
                                                      const int* __restrict__ cols,
                                                      const float* __restrict__ vals,
                                                      const unsigned int* __restrict__ row_start,
                                                      unsigned int* __restrict__ cnt,
                                                      uint2* __restrict__ binned) {
  unsigned int e = blockIdx.x * 256 + threadIdx.x;
  if (e >= NE) return;
  int r = rows[e];
  unsigned int off = atomicSub(&cnt[r], 1u) - 1u;   // deg-1 .. 0
  unsigned int pos = row_start[r] + off;
  binned[pos] = make_uint2((unsigned int)cols[e], __float_as_uint(vals[e]));
}

// ---- Kernel 5: gather-accumulate, one wave per node, no atomics ----
// lane l covers output cols 2l, 2l+1 (one uint = 2 bf16 of support per edge)
__global__ __launch_bounds__(256) void gather_kernel(const unsigned int* __restrict__ row_start,
                                                     const uint2* __restrict__ binned,
                                                     const unsigned int* __restrict__ support_u,
                                                     float* __restrict__ out) {
  int node = blockIdx.x * 4 + (threadIdx.x >> 6);
  if (node >= NN) return;
  int lane = threadIdx.x & 63;
  unsigned int i   = row_start[node];
  unsigned int end = row_start[node + 1];
  float a0 = 0.f, a1 = 0.f;
  // 2-edge unroll for independent load chains
  for (; i + 2 <= end; i += 2) {
    uint2 e0 = binned[i];
    uint2 e1 = binned[i + 1];
    unsigned int sA = support_u[(size_t)e0.x * 64 + lane];
    unsigned int sB = support_u[(size_t)e1.x * 64 + lane];
    float v0 = __uint_as_float(e0.y);
    float v1 = __uint_as_float(e1.y);
    a0 = fmaf(v0, __uint_as_float(sA << 16), a0);
    a1 = fmaf(v0, __uint_as_float(sA & 0xFFFF0000u), a1);
    a0 = fmaf(v1, __uint_as_float(sB << 16), a0);
    a1 = fmaf(v1, __uint_as_float(sB & 0xFFFF0000u), a1);
  }
  if (i < end) {
    uint2 e0 = binned[i];
    unsigned int sA = support_u[(size_t)e0.x * 64 + lane];
    float v0 = __uint_as_float(e0.y);
    a0 = fmaf(v0, __uint_as_float(sA << 16), a0);
    a1 = fmaf(v0, __uint_as_float(sA & 0xFFFF0000u), a1);
  }
  float2 o = make_float2(a0, a1);
  *(float2*)(out + (size_t)node * MF + lane * 2) = o;
}

extern "C" void kernel_launch(void* const* d_in, const int* in_sizes, int n_in,
                              void* d_out, int out_size, void* d_ws, size_t ws_size,
                              hipStream_t stream) {
  const float* x    = (const float*)d_in[0];
  const int*   rows = (const int*)d_in[1];
  const int*   cols = (const int*)d_in[2];
  const float* vals = (const float*)d_in[3];
  const float* W    = (const float*)d_in[4];
  const float* bias = (const float*)d_in[5];

  char* ws = (char*)d_ws;
  unsigned short* Wt        = (unsigned short*)ws;                          // 65,536 B
  unsigned short* support   = (unsigned short*)(ws + 65536);                // 25,600,000 B
  unsigned int*   cnt       = (unsigned int*)(ws + 65536 + 25600000ull);    // 400,000 B
  unsigned int*   row_start = (unsigned int*)(ws + 65536 + 26000000ull);    // 400,004 B
  uint2*          binned    = (uint2*)(ws + 65536 + 26400064ull);           // 25,600,000 B
  // total ws use: ~52.07 MB

  hipMemsetAsync(cnt, 0, 400000ull, stream);
  wt_kernel<<<128, 256, 0, stream>>>(W, Wt);
  gemm_kernel<<<(NN + 63) / 64, 256, 0, stream>>>(x, Wt, bias, support);
  hist_kernel<<<(NE + 255) / 256, 256, 0, stream>>>(rows, cnt);
  scan_kernel<<<1, 1024, 0, stream>>>(cnt, row_start);
  scatter_kernel<<<(NE + 255) / 256, 256, 0, stream>>>(rows, cols, vals, row_start, cnt, binned);
  gather_kernel<<<(NN + 3) / 4, 256, 0, stream>>>(row_start, binned,
                                                  (const unsigned int*)support, (float*)d_out);
}

// Round 4
// 616.095 us; speedup vs baseline: 8.9656x; 1.1291x over previous
//
#include <hip/hip_runtime.h>
#include <stdint.h>

#define NN 100000
#define NE 3200000
#define KF 256   // in features
#define MF 128   // out features
#define NB_SCAN ((NN + 255) / 256)   // 391

typedef __attribute__((ext_vector_type(8))) short bf16x8;
typedef __attribute__((ext_vector_type(4))) float floatx4;

__device__ __forceinline__ float bf2f(unsigned short u) {
  union { unsigned int i; float f; } w; w.i = ((unsigned int)u) << 16; return w.f;
}
__device__ __forceinline__ unsigned short f2bf(float f) {
  union { float f; unsigned int i; } w; w.f = f;
  unsigned int u = w.i;
  u += 0x7FFFu + ((u >> 16) & 1u);   // round-to-nearest-even
  return (unsigned short)(u >> 16);
}

// ---- Kernel 0: W [K=256][M=128] fp32 -> Wt [M=128][K=256] bf16 ----
__global__ __launch_bounds__(256) void wt_kernel(const float* __restrict__ W,
                                                 unsigned short* __restrict__ Wt) {
  int idx = blockIdx.x * 256 + threadIdx.x;   // 32768 total
  int k = idx >> 7;
  int c = idx & 127;
  Wt[(size_t)c * KF + k] = f2bf(W[(size_t)k * MF + c]);
}

// ---- Kernel 1: support = x @ W + b (fp32 -> bf16 staging -> MFMA -> bf16) ----
__global__ __launch_bounds__(256) void gemm_kernel(const float* __restrict__ x,
                                                   const unsigned short* __restrict__ Wt,
                                                   const float* __restrict__ bias,
                                                   unsigned short* __restrict__ support) {
  __shared__ unsigned short Ax[64][136];
  __shared__ unsigned short Wl[128][136];
  const int tid = threadIdx.x;
  const int row0 = blockIdx.x * 64;
  const int lane = tid & 63;
  const int wv = tid >> 6;
  const int m = lane & 15;
  const int quad = lane >> 4;

  floatx4 acc[8];
#pragma unroll
  for (int t = 0; t < 8; ++t) acc[t] = (floatx4){0.f, 0.f, 0.f, 0.f};

  for (int kb = 0; kb < 2; ++kb) {
    if (kb) __syncthreads();
#pragma unroll
    for (int i = 0; i < 8; ++i) {
      int u = tid + i * 256;
      int r = u >> 5;
      int q = u & 31;
      float4 v = make_float4(0.f, 0.f, 0.f, 0.f);
      if (row0 + r < NN)
        v = *(const float4*)(x + (size_t)(row0 + r) * KF + kb * 128 + q * 4);
      ushort4 p;
      p.x = f2bf(v.x); p.y = f2bf(v.y); p.z = f2bf(v.z); p.w = f2bf(v.w);
      *(ushort4*)(&Ax[r][q * 4]) = p;
    }
#pragma unroll
    for (int i = 0; i < 8; ++i) {
      int u = tid + i * 256;
      int c = u >> 4, kq = u & 15;
      *(uint4*)(&Wl[c][kq * 8]) = *(const uint4*)(Wt + (size_t)c * KF + kb * 128 + kq * 8);
    }
    __syncthreads();
#pragma unroll
    for (int kc = 0; kc < 4; ++kc) {
      int k0 = kc * 32 + quad * 8;
      bf16x8 af = *(const bf16x8*)(&Ax[wv * 16 + m][k0]);
#pragma unroll
      for (int ct = 0; ct < 8; ++ct) {
        bf16x8 bfv = *(const bf16x8*)(&Wl[ct * 16 + m][k0]);
        acc[ct] = __builtin_amdgcn_mfma_f32_16x16x32_bf16(af, bfv, acc[ct], 0, 0, 0);
      }
    }
  }
#pragma unroll
  for (int ct = 0; ct < 8; ++ct) {
    int col = ct * 16 + m;
    float bv = bias[col];
#pragma unroll
    for (int rg = 0; rg < 4; ++rg) {
      int grow = row0 + wv * 16 + quad * 4 + rg;
      if (grow < NN)
        support[(size_t)grow * MF + col] = f2bf(acc[ct][rg] + bv);
    }
  }
}

// ---- Kernel 2: histogram of destination rows ----
__global__ __launch_bounds__(256) void hist_kernel(const int* __restrict__ rows,
                                                   unsigned int* __restrict__ cnt) {
  unsigned int e = blockIdx.x * 256 + threadIdx.x;
  if (e < NE) atomicAdd(&cnt[rows[e]], 1u);
}

// ---- Kernel 3a: per-block partial sums of cnt (256 elems/block) ----
__global__ __launch_bounds__(256) void scan_partial(const unsigned int* __restrict__ cnt,
                                                    unsigned int* __restrict__ partial) {
  int gi = blockIdx.x * 256 + threadIdx.x;
  int lane = threadIdx.x & 63;
  int wv = threadIdx.x >> 6;
  unsigned int v = (gi < NN) ? cnt[gi] : 0u;
#pragma unroll
  for (int d = 1; d < 64; d <<= 1) v += __shfl_xor(v, d, 64);
  __shared__ unsigned int ws4[4];
  if (lane == 0) ws4[wv] = v;
  __syncthreads();
  if (threadIdx.x == 0) partial[blockIdx.x] = ws4[0] + ws4[1] + ws4[2] + ws4[3];
}

// ---- Kernel 3b: single-block exclusive scan of the 391 partials (in place) ----
__global__ __launch_bounds__(512) void scan_tops(unsigned int* __restrict__ partial) {
  const int tid = threadIdx.x;
  const int lane = tid & 63;
  const int wv = tid >> 6;   // 8 waves
  unsigned int v = (tid < NB_SCAN) ? partial[tid] : 0u;
  unsigned int inc = v;
#pragma unroll
  for (int d = 1; d < 64; d <<= 1) {
    unsigned int n = __shfl_up(inc, d, 64);
    if (lane >= d) inc += n;
  }
  __shared__ unsigned int ws8[8];
  if (lane == 63) ws8[wv] = inc;
  __syncthreads();
  if (wv == 0 && lane < 8) {
    unsigned int w = ws8[lane], winc = w;
#pragma unroll
    for (int d = 1; d < 8; d <<= 1) {
      unsigned int n = __shfl_up(winc, d, 64);
      if (lane >= d) winc += n;
    }
    ws8[lane] = winc - w;     // exclusive wave prefix
  }
  __syncthreads();
  if (tid < NB_SCAN) partial[tid] = ws8[wv] + inc - v;   // exclusive scan
}

// ---- Kernel 3c: final exclusive scan: row_start = scan(cnt) + partial[block] ----
__global__ __launch_bounds__(256) void scan_final(const unsigned int* __restrict__ cnt,
                                                  const unsigned int* __restrict__ partial,
                                                  unsigned int* __restrict__ row_start) {
  int gi = blockIdx.x * 256 + threadIdx.x;
  const int tid = threadIdx.x;
  const int lane = tid & 63;
  const int wv = tid >> 6;
  unsigned int v = (gi < NN) ? cnt[gi] : 0u;
  unsigned int inc = v;
#pragma unroll
  for (int d = 1; d < 64; d <<= 1) {
    unsigned int n = __shfl_up(inc, d, 64);
    if (lane >= d) inc += n;
  }
  __shared__ unsigned int ws4[4];
  __shared__ unsigned int woff[4];
  if (lane == 63) ws4[wv] = inc;
  __syncthreads();
  if (tid == 0) {
    unsigned int r = 0;
#pragma unroll
    for (int k = 0; k < 4; ++k) { woff[k] = r; r += ws4[k]; }
  }
  __syncthreads();
  if (gi < NN) row_start[gi] = partial[blockIdx.x] + woff[wv] + inc - v;
  if (gi == 0) row_start[NN] = NE;
}

// ---- Kernel 4: scatter edges into row-binned array (packed col+val, 8 B) ----
__global__ __launch_bounds__(256) void scatter_kernel(const int* __restrict__ rows,
                                                      const int* __restrict__ cols,
                                                      const float* __restrict__ vals,
                                                      const unsigned int* __restrict__ row_start,
                                                      unsigned int* __restrict__ cnt,
                                                      uint2* __restrict__ binned) {
  unsigned int e = blockIdx.x * 256 + threadIdx.x;
  if (e >= NE) return;
  int r = rows[e];
  unsigned int off = atomicSub(&cnt[r], 1u) - 1u;   // deg-1 .. 0
  unsigned int pos = row_start[r] + off;
  binned[pos] = make_uint2((unsigned int)cols[e], __float_as_uint(vals[e]));
}

// ---- Kernel 5: gather-accumulate, one wave per node, half-wave edge-parallel ----
// lanes 0-31 process even edges, lanes 32-63 odd edges; lane hl covers cols 4hl..4hl+3
__global__ __launch_bounds__(256) void gather_kernel(const unsigned int* __restrict__ row_start,
                                                     const uint2* __restrict__ binned,
                                                     const unsigned int* __restrict__ support_u,
                                                     float* __restrict__ out) {
  int node = blockIdx.x * 4 + (threadIdx.x >> 6);
  if (node >= NN) return;
  int lane = threadIdx.x & 63;
  int half = lane >> 5;
  int hl = lane & 31;
  unsigned int i   = row_start[node];
  unsigned int end = row_start[node + 1];
  float a0 = 0.f, a1 = 0.f, a2 = 0.f, a3 = 0.f;
  // 4 edges per iteration: 2 per half-wave, 2 independent 8B loads per lane in flight
  for (; i + 4 <= end; i += 4) {
    uint2 eA = binned[i + half];
    uint2 eB = binned[i + 2 + half];
    uint2 sA = *(const uint2*)(support_u + (size_t)eA.x * 64 + hl * 2);
    uint2 sB = *(const uint2*)(support_u + (size_t)eB.x * 64 + hl * 2);
    float vA = __uint_as_float(eA.y);
    float vB = __uint_as_float(eB.y);
    a0 = fmaf(vA, __uint_as_float(sA.x << 16), a0);
    a1 = fmaf(vA, __uint_as_float(sA.x & 0xFFFF0000u), a1);
    a2 = fmaf(vA, __uint_as_float(sA.y << 16), a2);
    a3 = fmaf(vA, __uint_as_float(sA.y & 0xFFFF0000u), a3);
    a0 = fmaf(vB, __uint_as_float(sB.x << 16), a0);
    a1 = fmaf(vB, __uint_as_float(sB.x & 0xFFFF0000u), a1);
    a2 = fmaf(vB, __uint_as_float(sB.y << 16), a2);
    a3 = fmaf(vB, __uint_as_float(sB.y & 0xFFFF0000u), a3);
  }
  if (i + 2 <= end) {
    uint2 eA = binned[i + half];
    uint2 sA = *(const uint2*)(support_u + (size_t)eA.x * 64 + hl * 2);
    float vA = __uint_as_float(eA.y);
    a0 = fmaf(vA, __uint_as_float(sA.x << 16), a0);
    a1 = fmaf(vA, __uint_as_float(sA.x & 0xFFFF0000u), a1);
    a2 = fmaf(vA, __uint_as_float(sA.y << 16), a2);
    a3 = fmaf(vA, __uint_as_float(sA.y & 0xFFFF0000u), a3);
    i += 2;
  }
  if (i < end && half == 0) {        // single leftover edge: half-wave 0 only
    uint2 eA = binned[i];
    uint2 sA = *(const uint2*)(support_u + (size_t)eA.x * 64 + hl * 2);
    float vA = __uint_as_float(eA.y);
    a0 = fmaf(vA, __uint_as_float(sA.x << 16), a0);
    a1 = fmaf(vA, __uint_as_float(sA.x & 0xFFFF0000u), a1);
    a2 = fmaf(vA, __uint_as_float(sA.y << 16), a2);
    a3 = fmaf(vA, __uint_as_float(sA.y & 0xFFFF0000u), a3);
  }
  // combine half-waves: lanes 0..31 += lanes 32..63 (hl+32 is identity for upper half)
  a0 += __shfl(a0, hl + 32);
  a1 += __shfl(a1, hl + 32);
  a2 += __shfl(a2, hl + 32);
  a3 += __shfl(a3, hl + 32);
  if (half == 0) {
    float4 o = make_float4(a0, a1, a2, a3);
    *(float4*)(out + (size_t)node * MF + hl * 4) = o;
  }
}

extern "C" void kernel_launch(void* const* d_in, const int* in_sizes, int n_in,
                              void* d_out, int out_size, void* d_ws, size_t ws_size,
                              hipStream_t stream) {
  const float* x    = (const float*)d_in[0];
  const int*   rows = (const int*)d_in[1];
  const int*   cols = (const int*)d_in[2];
  const float* vals = (const float*)d_in[3];
  const float* W    = (const float*)d_in[4];
  const float* bias = (const float*)d_in[5];

  char* ws = (char*)d_ws;
  unsigned short* Wt        = (unsigned short*)ws;                          // 65,536 B
  unsigned short* support   = (unsigned short*)(ws + 65536);                // 25,600,000 B
  unsigned int*   cnt       = (unsigned int*)(ws + 65536 + 25600000ull);    // 400,000 B
  unsigned int*   row_start = (unsigned int*)(ws + 65536 + 26000000ull);    // 400,004 B
  uint2*          binned    = (uint2*)(ws + 65536 + 26400064ull);           // 25,600,000 B
  unsigned int*   partial   = (unsigned int*)(ws + 65536 + 52000064ull);    // 1,564 B
  // total ws use: ~52.07 MB

  hipMemsetAsync(cnt, 0, 400000ull, stream);
  wt_kernel<<<128, 256, 0, stream>>>(W, Wt);
  gemm_kernel<<<(NN + 63) / 64, 256, 0, stream>>>(x, Wt, bias, support);
  hist_kernel<<<(NE + 255) / 256, 256, 0, stream>>>(rows, cnt);
  scan_partial<<<NB_SCAN, 256, 0, stream>>>(cnt, partial);
  scan_tops<<<1, 512, 0, stream>>>(partial);
  scan_final<<<NB_SCAN, 256, 0, stream>>>(cnt, partial, row_start);
  scatter_kernel<<<(NE + 255) / 256, 256, 0, stream>>>(rows, cols, vals, row_start, cnt, binned);
  gather_kernel<<<(NN + 3) / 4, 256, 0, stream>>>(row_start, binned,
                                                  (const unsigned int*)support, (float*)d_out);
}